// Round 1
// baseline (196.614 us; speedup 1.0000x reference)
//
#include <hip/hip_runtime.h>
#include <hip/hip_bf16.h>
#include <cstdint>

// CTC forward loss (keras ctc_batch_cost semantics), B=64 T=1024 L=128 V=512.
// Probability-domain scaled forward algorithm:
//   alpha_new[s] = (alpha[s] + alpha[s-1] + allow_skip[s]*alpha[s-2]) * (p_t[ext[s]] + EPS)
// with power-of-2 renormalization every 4 steps (exact exponent bookkeeping).
// One wave per batch row; lane j owns states 4j..4j+3 (lane 63 also state 256).

#define CTC_B 64
#define CTC_T 1024
#define CTC_L 128
#define CTC_V 512
#define BLANK (CTC_V - 1)
#define EPSF 1e-7f
#define DPF 8   // prefetch depth (time steps)

__global__ __launch_bounds__(64, 1)
void ctc_fwd_kernel(const int* __restrict__ y_true,
                    const float* __restrict__ y_pred,
                    float* __restrict__ out) {
    const int b = blockIdx.x;
    const int j = threadIdx.x;  // lane 0..63
    const float* __restrict__ yb = y_pred + (size_t)b * CTC_T * CTC_V;

    // labels owned by this lane: states 4j+1 -> lab[2j], 4j+3 -> lab[2j+1]
    const int labA = y_true[b * CTC_L + 2 * j];
    const int labB = y_true[b * CTC_L + 2 * j + 1];
    const int labPrev = __shfl_up(labB, 1);  // lab[2j-1] (junk at lane 0, unused)

    // skip-transition masks (blank states never skip)
    const float msk1 = (labA != labPrev) ? 1.0f : 0.0f;  // state 4j+1 (lane0: pm1==0 anyway)
    const float msk3 = (labB != labA) ? 1.0f : 0.0f;     // state 4j+3

    // t = 0 init: only states 0 (blank) and 1 (first label) alive
    float a0 = 0.0f, a1 = 0.0f, a2 = 0.0f, a3 = 0.0f, a4 = 0.0f;
    {
        const float pb0 = yb[BLANK] + EPSF;
        const float pl0 = yb[labA] + EPSF;  // lane 0's labA == lab[0]
        if (j == 0) { a0 = pb0; a1 = pl0; }
    }

    int Eacc = 0;  // accumulated power-of-2 exponent from renormalization

    // prefetch slots: slot k holds row (group_base + k)'s three probs
    float pfb[DPF], pfa[DPF], pfc[DPF];
#pragma unroll
    for (int k = 0; k < DPF; ++k) {
        const float* rw = yb + (size_t)(1 + k) * CTC_V;
        pfb[k] = rw[BLANK];
        pfa[k] = rw[labA];
        pfc[k] = rw[labB];
    }

#define RENORM do {                                                        \
        float m = fmaxf(fmaxf(fmaxf(a0, a1), fmaxf(a2, a3)), a4);          \
        m = fmaxf(m, __shfl_xor(m, 1));                                    \
        m = fmaxf(m, __shfl_xor(m, 2));                                    \
        m = fmaxf(m, __shfl_xor(m, 4));                                    \
        m = fmaxf(m, __shfl_xor(m, 8));                                    \
        m = fmaxf(m, __shfl_xor(m, 16));                                   \
        m = fmaxf(m, __shfl_xor(m, 32));                                   \
        int e = (int)((__float_as_uint(m) >> 23) & 255u) - 127;            \
        float sc = __uint_as_float((unsigned)(127 - e) << 23);             \
        a0 *= sc; a1 *= sc; a2 *= sc; a3 *= sc; a4 *= sc;                  \
        Eacc += e;                                                         \
    } while (0)

    // One time step. kk is a compile-time literal (slot index stays static).
    // Renorm when global step t = tb+kk satisfies t % 4 == 0; tb ≡ 1 (mod 8)
    // so that is kk == 3 or kk == 7.
#define STEP(kk, DO_PF) do {                                               \
        const float pb = pfb[kk] + EPSF;                                   \
        const float pA = pfa[kk] + EPSF;                                   \
        const float pB = pfc[kk] + EPSF;                                   \
        float pm1 = __shfl_up(a3, 1);                                      \
        pm1 = (j == 0) ? 0.0f : pm1;                                       \
        const float n0 = (a0 + pm1) * pb;                                  \
        const float n1 = fmaf(msk1, pm1, a0 + a1) * pA;                    \
        const float n2 = (a1 + a2) * pb;                                   \
        const float n3 = fmaf(msk3, a1, a2 + a3) * pB;                     \
        const float n4 = (a3 + a4) * pb;                                   \
        a0 = n0; a1 = n1; a2 = n2; a3 = n3; a4 = n4;                       \
        if (DO_PF) {                                                       \
            const int tn = tb + (kk) + DPF;                                \
            if (tn < CTC_T) {                                              \
                const float* rw = yb + (size_t)tn * CTC_V;                 \
                pfb[kk] = rw[BLANK];                                       \
                pfa[kk] = rw[labA];                                        \
                pfc[kk] = rw[labB];                                        \
            }                                                              \
        }                                                                  \
        if ((((kk) + 1) & 3) == 0) { RENORM; }                             \
    } while (0)

    int tb = 1;
    for (; tb + DPF <= CTC_T; tb += DPF) {
        STEP(0, true); STEP(1, true); STEP(2, true); STEP(3, true);
        STEP(4, true); STEP(5, true); STEP(6, true); STEP(7, true);
    }
    // tail: tb == 1017, steps t = 1017..1023 (7 steps), slots 0..6
    STEP(0, false); STEP(1, false); STEP(2, false);
    STEP(3, false); STEP(4, false); STEP(5, false); STEP(6, false);

#undef STEP
#undef RENORM

    // final: logaddexp(alpha[S-1], alpha[S-2]) -> log(a4 + a3) on lane 63
    if (j == 63) {
        const float sum = a3 + a4;
        const float logp = logf(sum) + (float)Eacc * 0.69314718055994530942f;
        out[b] = -logp;
    }
}

extern "C" void kernel_launch(void* const* d_in, const int* in_sizes, int n_in,
                              void* d_out, int out_size, void* d_ws, size_t ws_size,
                              hipStream_t stream) {
    const int* y_true = (const int*)d_in[0];     // [B, L] int32
    const float* y_pred = (const float*)d_in[1]; // [B, T, V] float32
    float* out = (float*)d_out;                  // [B, 1] float32

    ctc_fwd_kernel<<<CTC_B, 64, 0, stream>>>(y_true, y_pred, out);
}